// Round 5
// baseline (84.574 us; speedup 1.0000x reference)
//
#include <hip/hip_runtime.h>

// Parallel-beam 2D forward projection (Radon), ray-driven bilinear.
// Full image in LDS as bf16, 2 zero guard rows/cols each side.
// lane = (tseg 0..3, det 0..15); per-unit union k-window (shfl min/max),
// lanes run independent contiguous chains; invalid samples are zeroed by
// clamping coords into the guard band (no per-sample compares).

#define NVOL 256
#define NANG 180
#define NDET 363

constexpr int RW        = 131;               // dwords per row (131 % 32 == 3)
constexpr int NROWS     = 260;               // ly = y+2; real 2..257; guards 0,1,258,259
constexpr int LDS_WORDS = NROWS * RW;        // 34060
constexpr size_t LDS_BYTES = (size_t)LDS_WORDS * 4;  // 136240 B -> 1 block/CU

constexpr int DCH = 16;                      // dets per unit
constexpr int NCH = 23;                      // ceil(363/16)
constexpr int NUB = NANG * NCH;              // 4140 units per batch

__device__ __forceinline__ unsigned pack_bf16x2(float a, float b) {
    unsigned ua = __builtin_bit_cast(unsigned, a);
    unsigned ub = __builtin_bit_cast(unsigned, b);
    ua += 0x7FFFu + ((ua >> 16) & 1u);       // round-to-nearest-even
    ub += 0x7FFFu + ((ub >> 16) & 1u);
    return (ua >> 16) | (ub & 0xFFFF0000u);
}

__global__ __launch_bounds__(1024, 4)
void proj_kernel(const float* __restrict__ img, float* __restrict__ out,
                 unsigned* __restrict__ cnt)
{
    extern __shared__ unsigned L[];
    const int tid   = threadIdx.x;
    const int batch = blockIdx.x & 1;

    // zero LDS (guards + pads)
    for (int i = tid; i < LDS_WORDS; i += 1024) L[i] = 0u;
    __syncthreads();

    // stage rows 0..255 -> ly = y+2; cols x -> lx = x+2 (bf16 pairs)
    const float4* img4 = (const float4*)(img + batch * (NVOL * NVOL));
    #pragma unroll
    for (int it = 0; it < 16; ++it) {
        int g = tid + (it << 10);
        int r = g >> 6, q = g & 63;
        float4 v = img4[g];
        int w = (r + 2) * RW + (q << 1) + 1;  // halves lx = 4q+2 .. 4q+5
        L[w]     = pack_bf16x2(v.x, v.y);
        L[w + 1] = pack_bf16x2(v.z, v.w);
    }
    __syncthreads();

    const int lane  = tid & 63;
    const int dlane = lane & 15;
    const int tseg  = lane >> 4;             // 0..3
    unsigned* ctr   = &cnt[batch << 5];
    float* outb     = out + batch * (NANG * NDET);
    const float B   = 128.5f;

    for (;;) {
        unsigned u = 0;
        if (lane == 0) u = atomicAdd(ctr, 1u);
        u = (unsigned)__builtin_amdgcn_readfirstlane((int)u);
        if (u >= (unsigned)NUB) break;

        int j = (int)(u / (unsigned)NANG);   // chunk order index 0..22
        int a = (int)(u - (unsigned)j * (unsigned)NANG);
        int ci = 11 + ((j + 1) >> 1) * ((j & 1) ? 1 : -1);   // center-out
        int det0 = ci << 4;
        int det  = det0 + dlane;

        float ang = (float)a * 0.017453292519943295f;
        float si = __sinf(ang), co = __cosf(ang);
        float rsi = __builtin_amdgcn_rcpf(si);
        float rco = __builtin_amdgcn_rcpf(co);
        float nsi = -si;

        // per-lane slab clip for own det
        float s  = (float)det - 181.0f;
        float sx = s * co, sy = s * si;
        float t1 = (sx - B) * rsi, t2 = (sx + B) * rsi;
        float tlo = fminf(t1, t2), thi = fmaxf(t1, t2);
        float u1 = (-B - sy) * rco, u2 = (B - sy) * rco;
        tlo = fmaxf(tlo, fminf(u1, u2));
        thi = fminf(thi, fmaxf(u1, u2));
        int k0 = (int)ceilf(tlo + 181.f);    // inf saturates, clamped below
        int k1 = (int)floorf(thi + 181.f);
        k0 = max(0, min(k0, 363));
        k1 = max(-1, min(k1, 362));
        if (k1 < k0 || det >= NDET) { k0 = 100000; k1 = -100000; }

        // union k-window across the 16 dets (uniform across tsegs too)
        int uk0 = k0, uk1 = k1;
        #pragma unroll
        for (int ms = 1; ms <= 8; ms <<= 1) {
            uk0 = min(uk0, __shfl_xor(uk0, ms));
            uk1 = max(uk1, __shfl_xor(uk1, ms));
        }
        int n = uk1 - uk0 + 1;

        float total = 0.f;
        if (n > 0) {
            int m = (n + 3) >> 2;            // samples per tseg (<= 91)
            float Ax = fmaf(181.f, si, sx) + 129.5f;   // fx(k) = Ax - k*si
            float Ay = fmaf(-181.f, co, sy) + 129.5f;  // fy(k) = Ay + k*co
            float kf = (float)(uk0 + tseg * m);
            float acc = 0.f;
            #pragma unroll 2
            for (int it2 = 0; it2 < m; ++it2, kf += 1.f) {
                float fx = fmaf(kf, nsi, Ax);
                float fy = fmaf(kf, co,  Ay);
                // clamp into guard band: out-of-support samples read zeros
                fx = fminf(fmaxf(fx, 0.5f), 258.5f);
                fy = fminf(fmaxf(fy, 0.5f), 258.5f);
                int ix = (int)fx, iy = (int)fy;
                float wx = fx - (float)ix;
                float wy = fy - (float)iy;
                const unsigned* row = &L[iy * RW + (ix >> 1)];
                unsigned wA0 = row[0],  wA1 = row[1];
                unsigned wB0 = row[RW], wB1 = row[RW + 1];
                unsigned sh = (unsigned)((ix & 1) << 4);
                unsigned p0 = __builtin_amdgcn_alignbit(wA1, wA0, sh);
                unsigned p1 = __builtin_amdgcn_alignbit(wB1, wB0, sh);
                float f0l = __builtin_bit_cast(float, p0 << 16);
                float f0h = __builtin_bit_cast(float, p0 & 0xFFFF0000u);
                float f1l = __builtin_bit_cast(float, p1 << 16);
                float f1h = __builtin_bit_cast(float, p1 & 0xFFFF0000u);
                float c0 = fmaf(wy, f1l - f0l, f0l);
                float c1 = fmaf(wy, f1h - f0h, f0h);
                acc += fmaf(wx, c1 - c0, c0);
            }
            acc += __shfl_xor(acc, 16);      // sum the 4 tsegs
            acc += __shfl_xor(acc, 32);
            total = acc;
        }
        if (lane < DCH && det < NDET)
            outb[a * NDET + det] = total;
    }
}

extern "C" void kernel_launch(void* const* d_in, const int* in_sizes, int n_in,
                              void* d_out, int out_size, void* d_ws, size_t ws_size,
                              hipStream_t stream) {
    const float* img = (const float*)d_in[0];
    float* out = (float*)d_out;
    unsigned* cnt = (unsigned*)d_ws;

    hipFuncSetAttribute((const void*)proj_kernel,
                        hipFuncAttributeMaxDynamicSharedMemorySize, (int)LDS_BYTES);
    hipMemsetAsync(d_ws, 0, 2 * 32 * sizeof(unsigned), stream);
    proj_kernel<<<256, 1024, LDS_BYTES, stream>>>(img, out, cnt);
}

// Round 6
// 28.761 us; speedup vs baseline: 2.9406x; 2.9406x over previous
//
#include <hip/hip_runtime.h>

// Parallel-beam 2D forward projection (Radon), ray-driven bilinear.
// Full image in LDS as bf16, 2 zero guard rows/cols each side.
// lane = (tseg 0..3, det 0..15); per-unit union k-window (shfl min/max),
// invalid samples zeroed by clamping coords into the guard band.
// R5: NO global work-stealing atomics (they serialized R0-R4 at ~76us).
// Static stride-128 unit slice per block + LDS-counter stealing among
// the block's 16 waves.

#define NVOL 256
#define NANG 180
#define NDET 363

constexpr int RW        = 131;               // dwords per row (131 % 32 == 3)
constexpr int NROWS     = 260;               // ly = y+2; real 2..257; guards 0,1,258,259
constexpr int LDS_WORDS = NROWS * RW;        // 34060
constexpr int LDS_TOTAL = LDS_WORDS + 32;    // + work counter (isolated line)
constexpr size_t LDS_BYTES = (size_t)LDS_TOTAL * 4;  // 136368 B -> 1 block/CU

constexpr int DCH = 16;                      // dets per unit
constexpr int NCH = 23;                      // ceil(363/16)
constexpr int NUB = NANG * NCH;              // 4140 units per batch
constexpr int BPB = 128;                     // blocks per batch

__device__ __forceinline__ unsigned pack_bf16x2(float a, float b) {
    unsigned ua = __builtin_bit_cast(unsigned, a);
    unsigned ub = __builtin_bit_cast(unsigned, b);
    ua += 0x7FFFu + ((ua >> 16) & 1u);       // round-to-nearest-even
    ub += 0x7FFFu + ((ub >> 16) & 1u);
    return (ua >> 16) | (ub & 0xFFFF0000u);
}

__global__ __launch_bounds__(1024, 4)
void proj_kernel(const float* __restrict__ img, float* __restrict__ out)
{
    extern __shared__ unsigned L[];
    const int tid   = threadIdx.x;
    const int batch = blockIdx.x & 1;
    const int bblk  = blockIdx.x >> 1;       // 0..127: slice index within batch

    // zero LDS (guards + pads + counter)
    for (int i = tid; i < LDS_TOTAL; i += 1024) L[i] = 0u;
    __syncthreads();

    // stage rows 0..255 -> ly = y+2; cols x -> lx = x+2 (bf16 pairs)
    const float4* img4 = (const float4*)(img + batch * (NVOL * NVOL));
    #pragma unroll
    for (int it = 0; it < 16; ++it) {
        int g = tid + (it << 10);
        int r = g >> 6, q = g & 63;
        float4 v = img4[g];
        int w = (r + 2) * RW + (q << 1) + 1;  // halves lx = 4q+2 .. 4q+5
        L[w]     = pack_bf16x2(v.x, v.y);
        L[w + 1] = pack_bf16x2(v.z, v.w);
    }
    __syncthreads();

    const int lane  = tid & 63;
    const int dlane = lane & 15;
    const int tseg  = lane >> 4;             // 0..3
    float* outb     = out + batch * (NANG * NDET);
    const float B   = 128.5f;
    unsigned* Lc    = &L[LDS_WORDS];         // block-local work counter

    for (;;) {
        unsigned i = 0;
        if (lane == 0) i = atomicAdd(Lc, 1u);          // ds_add_rtn_u32
        i = (unsigned)__builtin_amdgcn_readfirstlane((int)i);
        unsigned u = i * (unsigned)BPB + (unsigned)bblk;
        if (u >= (unsigned)NUB) break;

        int j = (int)(u / (unsigned)NANG);   // chunk order index 0..22
        int a = (int)(u - (unsigned)j * (unsigned)NANG);
        int ci = 11 + ((j + 1) >> 1) * ((j & 1) ? 1 : -1);   // center-out map
        int det0 = ci << 4;
        int det  = det0 + dlane;

        float ang = (float)a * 0.017453292519943295f;
        float si = __sinf(ang), co = __cosf(ang);
        float rsi = __builtin_amdgcn_rcpf(si);
        float rco = __builtin_amdgcn_rcpf(co);
        float nsi = -si;

        // per-lane slab clip for own det
        float s  = (float)det - 181.0f;
        float sx = s * co, sy = s * si;
        float t1 = (sx - B) * rsi, t2 = (sx + B) * rsi;
        float tlo = fminf(t1, t2), thi = fmaxf(t1, t2);
        float u1 = (-B - sy) * rco, u2 = (B - sy) * rco;
        tlo = fmaxf(tlo, fminf(u1, u2));
        thi = fminf(thi, fmaxf(u1, u2));
        int k0 = (int)ceilf(tlo + 181.f);    // inf saturates, clamped below
        int k1 = (int)floorf(thi + 181.f);
        k0 = max(0, min(k0, 363));
        k1 = max(-1, min(k1, 362));
        if (k1 < k0 || det >= NDET) { k0 = 100000; k1 = -100000; }

        // union k-window across the 16 dets (uniform across tsegs too)
        int uk0 = k0, uk1 = k1;
        #pragma unroll
        for (int ms = 1; ms <= 8; ms <<= 1) {
            uk0 = min(uk0, __shfl_xor(uk0, ms));
            uk1 = max(uk1, __shfl_xor(uk1, ms));
        }
        int n = uk1 - uk0 + 1;

        float total = 0.f;
        if (n > 0) {
            int m = (n + 3) >> 2;            // samples per tseg (<= 91)
            float Ax = fmaf(181.f, si, sx) + 129.5f;   // fx(k) = Ax - k*si
            float Ay = fmaf(-181.f, co, sy) + 129.5f;  // fy(k) = Ay + k*co
            float kf = (float)(uk0 + tseg * m);
            float acc = 0.f;
            #pragma unroll 4
            for (int it2 = 0; it2 < m; ++it2, kf += 1.f) {
                float fx = fmaf(kf, nsi, Ax);
                float fy = fmaf(kf, co,  Ay);
                // clamp into guard band: out-of-support samples read zeros
                fx = fminf(fmaxf(fx, 0.5f), 258.5f);
                fy = fminf(fmaxf(fy, 0.5f), 258.5f);
                int ix = (int)fx, iy = (int)fy;
                float wx = fx - (float)ix;
                float wy = fy - (float)iy;
                const unsigned* row = &L[iy * RW + (ix >> 1)];
                unsigned wA0 = row[0],  wA1 = row[1];
                unsigned wB0 = row[RW], wB1 = row[RW + 1];
                unsigned sh = (unsigned)((ix & 1) << 4);
                unsigned p0 = __builtin_amdgcn_alignbit(wA1, wA0, sh);
                unsigned p1 = __builtin_amdgcn_alignbit(wB1, wB0, sh);
                float f0l = __builtin_bit_cast(float, p0 << 16);
                float f0h = __builtin_bit_cast(float, p0 & 0xFFFF0000u);
                float f1l = __builtin_bit_cast(float, p1 << 16);
                float f1h = __builtin_bit_cast(float, p1 & 0xFFFF0000u);
                float c0 = fmaf(wy, f1l - f0l, f0l);
                float c1 = fmaf(wy, f1h - f0h, f0h);
                acc += fmaf(wx, c1 - c0, c0);
            }
            acc += __shfl_xor(acc, 16);      // sum the 4 tsegs
            acc += __shfl_xor(acc, 32);
            total = acc;
        }
        if (lane < DCH && det < NDET)
            outb[a * NDET + det] = total;
    }
}

extern "C" void kernel_launch(void* const* d_in, const int* in_sizes, int n_in,
                              void* d_out, int out_size, void* d_ws, size_t ws_size,
                              hipStream_t stream) {
    const float* img = (const float*)d_in[0];
    float* out = (float*)d_out;

    hipFuncSetAttribute((const void*)proj_kernel,
                        hipFuncAttributeMaxDynamicSharedMemorySize, (int)LDS_BYTES);
    proj_kernel<<<256, 1024, LDS_BYTES, stream>>>(img, out);
}